// Round 18
// baseline (797.861 us; speedup 1.0000x reference)
//
#include <hip/hip_runtime.h>
#include <math.h>

#define LB __launch_bounds__(256)

constexpr int BATCH = 32, NFEAT = 1024, FDIM = 768, NSLOT = 24;
constexpr int NH = 4, DH = 64, NITER = 3;
constexpr int MF = BATCH * NFEAT;   // 32768 feature rows
constexpr int MS = BATCH * NSLOT;   // 768 slot rows
constexpr int VQVIS_BLOCKS = MS + BATCH * NSLOT * NFEAT / 256;  // 768 + 3072
constexpr float QSCALE = 0.125f;    // dh^-0.5
constexpr float ATTN_EPS = 1e-8f;
constexpr float LNEPS = 1e-5f;

typedef __attribute__((ext_vector_type(8))) short bf16x8;
typedef __attribute__((ext_vector_type(4))) float f32x4;

__device__ __forceinline__ unsigned short f2bf(float x) {
  unsigned u = __float_as_uint(x);
  return (unsigned short)((u + 0x7FFFu + ((u >> 16) & 1u)) >> 16);
}
__device__ __forceinline__ float bf2f(unsigned short h) {
  return __uint_as_float(((unsigned)h) << 16);
}
__device__ __forceinline__ void cvt8(const float4& a, const float4& b, float m, float r,
                                     int4& hi, int4& lo) {
  float v[8] = {a.x, a.y, a.z, a.w, b.x, b.y, b.z, b.w};
  unsigned sh[8], sl[8];
#pragma unroll
  for (int j = 0; j < 8; ++j) {
    float vv = (v[j] - m) * r;
    unsigned short h = f2bf(vv);
    sh[j] = h;
    sl[j] = f2bf(vv - bf2f(h));
  }
  hi = make_int4((int)(sh[0] | (sh[1] << 16)), (int)(sh[2] | (sh[3] << 16)),
                 (int)(sh[4] | (sh[5] << 16)), (int)(sh[6] | (sh[7] << 16)));
  lo = make_int4((int)(sl[0] | (sl[1] << 16)), (int)(sl[2] | (sl[3] << 16)),
                 (int)(sl[4] | (sl[5] << 16)), (int)(sl[6] | (sl[7] << 16)));
}

// async 16B global->LDS
__device__ __forceinline__ void gll16(const void* g, void* l) {
  __builtin_amdgcn_global_load_lds(
      (const __attribute__((address_space(1))) void*)g,
      (__attribute__((address_space(3))) void*)l, 16, 0, 0);
}

// ---- merged: blocks [0,8192) rowstats; [8192,8960) weight prep; zeroes vq counter ----
__global__ LB void k_preprow(const float* __restrict__ x, float* __restrict__ stats,
                             const float* __restrict__ Wk, const float* __restrict__ Wv,
                             const float* __restrict__ Wq,
                             const float* __restrict__ g_in, const float* __restrict__ b_in,
                             const float* __restrict__ g_s, const float* __restrict__ b_s,
                             short* __restrict__ Bh_g, short* __restrict__ Bl_g,
                             short* __restrict__ Wgqh, short* __restrict__ Wgql,
                             float* __restrict__ cconst, unsigned* __restrict__ vqctr) {
  const int t = threadIdx.x;
  if (blockIdx.x == 0 && t == 0) *vqctr = 0u;
  if (blockIdx.x < MF / 4) {
    const int row = blockIdx.x * 4 + (t >> 6);
    const int lane = t & 63;
    const float* xr = x + (size_t)row * FDIM;
    float s = 0.f, sq = 0.f;
#pragma unroll
    for (int i = 0; i < 3; ++i) {
      float4 v = *(const float4*)(xr + i * 256 + lane * 4);
      s += v.x + v.y + v.z + v.w;
      sq += v.x * v.x + v.y * v.y + v.z * v.z + v.w * v.w;
    }
#pragma unroll
    for (int o = 32; o > 0; o >>= 1) { s += __shfl_down(s, o, 64); sq += __shfl_down(sq, o, 64); }
    if (lane == 0) {
      float m = s / (float)FDIM;
      float var = sq / (float)FDIM - m * m;
      stats[row * 2] = m;
      stats[row * 2 + 1] = 1.f / sqrtf(var + LNEPS);
    }
    return;
  }
  const int r = blockIdx.x - MF / 4;
  float s = 0.f;
  if (r < 512) {
    const float* srcW = (r < 256) ? (Wk + (size_t)r * FDIM) : (Wv + (size_t)(r - 256) * FDIM);
    for (int k = t; k < FDIM; k += 256) {
      float w = srcW[k];
      float wg = w * g_in[k];
      s += b_in[k] * w;
      unsigned short h = f2bf(wg);
      Bh_g[(size_t)r * FDIM + k] = (short)h;
      Bl_g[(size_t)r * FDIM + k] = (short)f2bf(wg - bf2f(h));
    }
  } else {
    const int c = r - 512;
    float w = Wq[(size_t)c * 256 + t];
    float wg = w * g_s[t];
    unsigned short hh = f2bf(wg);
    Wgqh[(size_t)c * 256 + t] = (short)hh;
    Wgql[(size_t)c * 256 + t] = (short)f2bf(wg - bf2f(hh));
    s = b_s[t] * w;
  }
  __shared__ float red[256];
  red[t] = s; __syncthreads();
  for (int o = 128; o > 0; o >>= 1) { if (t < o) red[t] += red[t + o]; __syncthreads(); }
  if (t == 0) cconst[r] = red[0];
}

// LDS union for k_mfkv: main-loop staging vs transpose-epilogue
union SmemM {
  struct { short Ah[2048], Al[2048], Bh[2][4096], Bl[2][4096]; } m;  // 40 KB
  struct { short vh[128][72], vl[128][72]; } e;                      // 36.9 KB
};

// -------- MFMA split-bf16: LN(features)@Wg^T -> k (bf16 hi/lo) AND vT (bf16 hi/lo) --------
__global__ LB void k_mfkv(const float* __restrict__ x, const float* __restrict__ stats,
                          const short* __restrict__ Bh_g, const short* __restrict__ Bl_g,
                          const float* __restrict__ cconst,
                          short* __restrict__ khi, short* __restrict__ klo,
                          short* __restrict__ vThi, short* __restrict__ vTlo) {
  __shared__ SmemM sm;
  const int t = threadIdx.x;
  const int l = t & 63;
  const int w = t >> 6;
  const int row0 = blockIdx.x * 64;
  const int c0 = blockIdx.y * 128;

  const int sAr = t >> 2;
  const int sl = t & 3;
  const int kqA = sl ^ ((sAr >> 1) & 3);
  const float* pa = x + (size_t)(row0 + sAr) * FDIM + kqA * 8;
  const float mA = stats[(row0 + sAr) * 2], rA = stats[(row0 + sAr) * 2 + 1];
  const int sBr1 = sAr + 64;
  const int kqB1 = sl ^ ((sBr1 >> 1) & 3);
  const short* pkh0 = Bh_g + (size_t)(c0 + sAr) * FDIM + kqA * 8;
  const short* pkh1 = Bh_g + (size_t)(c0 + sBr1) * FDIM + kqB1 * 8;
  const short* pkl0 = Bl_g + (size_t)(c0 + sAr) * FDIM + kqA * 8;
  const short* pkl1 = Bl_g + (size_t)(c0 + sBr1) * FDIM + kqB1 * 8;
  const short* pvh0 = Bh_g + (size_t)(256 + c0 + sAr) * FDIM + kqA * 8;
  const short* pvh1 = Bh_g + (size_t)(256 + c0 + sBr1) * FDIM + kqB1 * 8;
  const short* pvl0 = Bl_g + (size_t)(256 + c0 + sAr) * FDIM + kqA * 8;
  const short* pvl1 = Bl_g + (size_t)(256 + c0 + sBr1) * FDIM + kqB1 * 8;
  const int wbA = t * 16;
  const int wb0 = t * 16, wb1 = (t + 256) * 16;

  const int wm = (w >> 1) * 32, wn = (w & 1) * 64;
  int aoff[2], boff[4];
#pragma unroll
  for (int m = 0; m < 2; ++m) {
    const int ar = wm + m * 16 + (l & 15);
    const int kq = l >> 4;
    aoff[m] = ar * 64 + ((kq ^ ((ar >> 1) & 3)) << 4);
  }
#pragma unroll
  for (int n = 0; n < 4; ++n) {
    const int bc = wn + n * 16 + (l & 15);
    const int kq = l >> 4;
    boff[n] = bc * 64 + ((kq ^ ((bc >> 1) & 3)) << 4);
  }

  f32x4 acc[2][2][4] = {};
  float4 raa = *(const float4*)pa, rab = *(const float4*)(pa + 4);

  for (int s = 0; s < FDIM / 32; ++s) {
    if (s) __syncthreads();
    const int ko = s * 32;
    gll16(pkh0 + ko, (char*)&sm.m.Bh[0][0] + wb0);
    gll16(pkh1 + ko, (char*)&sm.m.Bh[0][0] + wb1);
    gll16(pkl0 + ko, (char*)&sm.m.Bl[0][0] + wb0);
    gll16(pkl1 + ko, (char*)&sm.m.Bl[0][0] + wb1);
    gll16(pvh0 + ko, (char*)&sm.m.Bh[1][0] + wb0);
    gll16(pvh1 + ko, (char*)&sm.m.Bh[1][0] + wb1);
    gll16(pvl0 + ko, (char*)&sm.m.Bl[1][0] + wb0);
    gll16(pvl1 + ko, (char*)&sm.m.Bl[1][0] + wb1);
    int4 hi, lo;
    cvt8(raa, rab, mA, rA, hi, lo);
    *(int4*)((char*)sm.m.Ah + wbA) = hi; *(int4*)((char*)sm.m.Al + wbA) = lo;
    if (s + 1 < FDIM / 32) {
      raa = *(const float4*)(pa + ko + 32);
      rab = *(const float4*)(pa + ko + 36);
    }
    __syncthreads();
    bf16x8 fah[2], fal[2];
#pragma unroll
    for (int m = 0; m < 2; ++m) {
      fah[m] = *(const bf16x8*)((const char*)sm.m.Ah + aoff[m]);
      fal[m] = *(const bf16x8*)((const char*)sm.m.Al + aoff[m]);
    }
#pragma unroll
    for (int kv = 0; kv < 2; ++kv) {
      bf16x8 fbh[4], fbl[4];
#pragma unroll
      for (int n = 0; n < 4; ++n) {
        fbh[n] = *(const bf16x8*)((const char*)&sm.m.Bh[kv][0] + boff[n]);
        fbl[n] = *(const bf16x8*)((const char*)&sm.m.Bl[kv][0] + boff[n]);
      }
#pragma unroll
      for (int m = 0; m < 2; ++m)
#pragma unroll
        for (int n = 0; n < 4; ++n) {
          acc[kv][m][n] = __builtin_amdgcn_mfma_f32_16x16x32_bf16(fal[m], fbh[n], acc[kv][m][n], 0, 0, 0);
          acc[kv][m][n] = __builtin_amdgcn_mfma_f32_16x16x32_bf16(fah[m], fbl[n], acc[kv][m][n], 0, 0, 0);
          acc[kv][m][n] = __builtin_amdgcn_mfma_f32_16x16x32_bf16(fah[m], fbh[n], acc[kv][m][n], 0, 0, 0);
        }
    }
  }
  __syncthreads();
  const int b_blk = row0 >> 10;
  const int jbase = row0 & 1023;
#pragma unroll
  for (int m = 0; m < 2; ++m) {
    const int rloc = wm + m * 16 + ((l >> 4) << 2);
    const int rbase = row0 + rloc;
#pragma unroll
    for (int n = 0; n < 4; ++n) {
      const int col = wn + n * 16 + (l & 15);
      const int gcol = c0 + col;
      const float cck = cconst[gcol];
      const float ccv = cconst[256 + gcol];
      unsigned vhp[2] = {0, 0}, vlp[2] = {0, 0};
#pragma unroll
      for (int r = 0; r < 4; ++r) {
        const float kval = acc[0][m][n][r] + cck;
        const unsigned short h = f2bf(kval);
        khi[(size_t)(rbase + r) * 256 + gcol] = (short)h;
        klo[(size_t)(rbase + r) * 256 + gcol] = (short)f2bf(kval - bf2f(h));
        const float vval = acc[1][m][n][r] + ccv;
        const unsigned short hv = f2bf(vval);
        const unsigned short lv = f2bf(vval - bf2f(hv));
        vhp[r >> 1] |= ((unsigned)hv) << ((r & 1) * 16);
        vlp[r >> 1] |= ((unsigned)lv) << ((r & 1) * 16);
      }
      *(int2*)((short*)&sm.e.vh[0][0] + col * 72 + rloc) = make_int2((int)vhp[0], (int)vhp[1]);
      *(int2*)((short*)&sm.e.vl[0][0] + col * 72 + rloc) = make_int2((int)vlp[0], (int)vlp[1]);
    }
  }
  __syncthreads();
  {
    const int vr = t >> 1;
    const int vh2 = (t & 1) * 32;
    const int gcol = c0 + vr;
    const int hh2 = gcol >> 6, dh = gcol & 63;
    const size_t vrow = ((size_t)(b_blk * 4 + hh2) * 64 + dh) * 1024 + jbase + vh2;
    const short* sh2 = (const short*)&sm.e.vh[0][0] + vr * 72 + vh2;
    const short* sl2 = (const short*)&sm.e.vl[0][0] + vr * 72 + vh2;
#pragma unroll
    for (int q = 0; q < 4; ++q) {
      *(int4*)(vThi + vrow + q * 8) = *(const int4*)(sh2 + q * 8);
      *(int4*)(vTlo + vrow + q * 8) = *(const int4*)(sl2 + q * 8);
    }
  }
}

// ---- fused full-MFMA fdots: register-LN + arena aliasing + K/V reg prefetch ----
template <bool WRITE_ATTN>
__global__ LB void k_fdots(const float* __restrict__ slots,
                           const short* __restrict__ Wgqh, const short* __restrict__ Wgql,
                           const float* __restrict__ cconst,
                           const short* __restrict__ khi, const short* __restrict__ klo,
                           const short* __restrict__ vThi, const short* __restrict__ vTlo,
                           float* __restrict__ attn, float* __restrict__ updp,
                           float* __restrict__ ssump) {
  const int blk = blockIdx.x;
  const int jc = blk & 3;
  const int h = (blk >> 2) & 3;
  const int b = blk >> 4;
  const int t = threadIdx.x;
  const int l = t & 63;
  const int w = t >> 6;
  __shared__ __attribute__((aligned(16))) char arena[32768];
  short* snh = (short*)arena;
  short* snl = (short*)(arena + 16384);
  float* scF = (float*)arena;
  __shared__ short qh[2048], ql[2048];
  __shared__ float part[4][NSLOT];

  const short* khb = khi + (size_t)(b * NFEAT + jc * 256) * 256 + h * 64;
  const short* klb = klo + (size_t)(b * NFEAT + jc * 256) * 256 + h * 64;
  bf16x8 kreg[16];
#pragma unroll
  for (int ks = 0; ks < 2; ++ks)
#pragma unroll
    for (int nl = 0; nl < 4; ++nl) {
      const int nt = w * 4 + nl;
      const size_t boffg = (size_t)(nt * 16 + (l & 15)) * 256 + ks * 32 + (l >> 4) * 8;
      kreg[(ks * 4 + nl) * 2 + 0] = *(const bf16x8*)(khb + boffg);
      kreg[(ks * 4 + nl) * 2 + 1] = *(const bf16x8*)(klb + boffg);
    }

  if (t < 192) {
    const int r = t >> 3, g = t & 7;
    const float* sr = slots + (size_t)(b * NSLOT + r) * 256 + g * 32;
    float4 va[8];
    float s = 0.f, sq = 0.f;
#pragma unroll
    for (int m4 = 0; m4 < 8; ++m4) {
      va[m4] = *(const float4*)(sr + m4 * 4);
      s += va[m4].x + va[m4].y + va[m4].z + va[m4].w;
      sq += va[m4].x * va[m4].x + va[m4].y * va[m4].y +
            va[m4].z * va[m4].z + va[m4].w * va[m4].w;
    }
    s += __shfl_down(s, 4, 8); sq += __shfl_down(sq, 4, 8);
    s += __shfl_down(s, 2, 8); sq += __shfl_down(sq, 2, 8);
    s += __shfl_down(s, 1, 8); sq += __shfl_down(sq, 1, 8);
    const float st = __shfl(s, l & 56, 64);
    const float sqt = __shfl(sq, l & 56, 64);
    const float mm = st * (1.f / 256.f);
    const float rr = 1.f / sqrtf(sqt * (1.f / 256.f) - mm * mm + LNEPS);
#pragma unroll
    for (int m4 = 0; m4 < 8; m4 += 2) {
      int4 hi, lo;
      cvt8(va[m4], va[m4 + 1], mm, rr, hi, lo);
      const int gi = g * 4 + (m4 >> 1);
      const int slot = r * 32 + (gi ^ (r & 31));
      *(int4*)&snh[slot * 8] = hi;
      *(int4*)&snl[slot * 8] = lo;
    }
  }
  __syncthreads();
  {
    f32x4 qacc[2] = {};
#pragma unroll
    for (int ks = 0; ks < 8; ++ks) {
      bf16x8 ah[2], al[2];
#pragma unroll
      for (int m = 0; m < 2; ++m) {
        const int row = m * 16 + (l & 15);
        const int g = ks * 4 + (l >> 4);
        const int slot = row * 32 + (g ^ (row & 31));
        ah[m] = *(const bf16x8*)&snh[slot * 8];
        al[m] = *(const bf16x8*)&snl[slot * 8];
      }
      const size_t brow = (size_t)(h * 64 + w * 16 + (l & 15)) * 256 + ks * 32 + (l >> 4) * 8;
      const bf16x8 bh = *(const bf16x8*)(Wgqh + brow);
      const bf16x8 bl2 = *(const bf16x8*)(Wgql + brow);
#pragma unroll
      for (int m = 0; m < 2; ++m) {
        qacc[m] = __builtin_amdgcn_mfma_f32_16x16x32_bf16(al[m], bh, qacc[m], 0, 0, 0);
        qacc[m] = __builtin_amdgcn_mfma_f32_16x16x32_bf16(ah[m], bl2, qacc[m], 0, 0, 0);
        qacc[m] = __builtin_amdgcn_mfma_f32_16x16x32_bf16(ah[m], bh, qacc[m], 0, 0, 0);
      }
    }
    const int d = w * 16 + (l & 15);
    const float qc = cconst[512 + h * 64 + d];
#pragma unroll
    for (int m = 0; m < 2; ++m)
#pragma unroll
      for (int r = 0; r < 4; ++r) {
        const int row = m * 16 + (l >> 4) * 4 + r;
        const float qv = qacc[m][r] + qc;
        const unsigned short hh = f2bf(qv);
        const int slot = row * 8 + ((d >> 3) ^ (row & 7));
        qh[slot * 8 + (d & 7)] = (short)hh;
        ql[slot * 8 + (d & 7)] = (short)f2bf(qv - bf2f(hh));
      }
  }
  __syncthreads();
  {
    f32x4 scc[2][4] = {};
#pragma unroll
    for (int ks = 0; ks < 2; ++ks) {
      bf16x8 ah[2], al[2];
#pragma unroll
      for (int m = 0; m < 2; ++m) {
        const int row = m * 16 + (l & 15);
        const int g = ks * 4 + (l >> 4);
        const int slot = row * 8 + (g ^ (row & 7));
        ah[m] = *(const bf16x8*)&qh[slot * 8];
        al[m] = *(const bf16x8*)&ql[slot * 8];
      }
#pragma unroll
      for (int nl = 0; nl < 4; ++nl) {
        const bf16x8 bh = kreg[(ks * 4 + nl) * 2 + 0];
        const bf16x8 bl2 = kreg[(ks * 4 + nl) * 2 + 1];
#pragma unroll
        for (int m = 0; m < 2; ++m) {
          scc[m][nl] = __builtin_amdgcn_mfma_f32_16x16x32_bf16(al[m], bh, scc[m][nl], 0, 0, 0);
          scc[m][nl] = __builtin_amdgcn_mfma_f32_16x16x32_bf16(ah[m], bl2, scc[m][nl], 0, 0, 0);
          scc[m][nl] = __builtin_amdgcn_mfma_f32_16x16x32_bf16(ah[m], bh, scc[m][nl], 0, 0, 0);
        }
      }
    }
#pragma unroll
    for (int m = 0; m < 2; ++m)
#pragma unroll
      for (int nl = 0; nl < 4; ++nl) {
        const int col = (w * 4 + nl) * 16 + (l & 15);
        const int rbase = m * 16 + ((l >> 4) << 2);
#pragma unroll
        for (int r = 0; r < 4; ++r)
          if (rbase + r < 24) scF[(rbase + r) * 256 + col] = scc[m][nl][r];
      }
  }
  bf16x8 vreg[16];
#pragma unroll
  for (int ks = 0; ks < 8; ++ks) {
    const size_t brow = ((size_t)(b * 4 + h) * 64 + w * 16 + (l & 15)) * 1024 +
                        jc * 256 + ks * 32 + (l >> 4) * 8;
    vreg[ks * 2 + 0] = *(const bf16x8*)(vThi + brow);
    vreg[ks * 2 + 1] = *(const bf16x8*)(vTlo + brow);
  }
  __syncthreads();
  float acc[NSLOT];
#pragma unroll
  for (int i = 0; i < NSLOT; ++i) acc[i] = scF[i * 256 + t];
  __syncthreads();
  {
    float mx = -1e30f;
#pragma unroll
    for (int i = 0; i < NSLOT; ++i) { acc[i] *= QSCALE; mx = fmaxf(mx, acc[i]); }
    float s = 0.f;
#pragma unroll
    for (int i = 0; i < NSLOT; ++i) { acc[i] = expf(acc[i] - mx); s += acc[i]; }
    const float inv = 1.f / s;
    float* ab = attn + (size_t)(b * NH + h) * NSLOT * NFEAT + jc * 256 + t;
#pragma unroll
    for (int i = 0; i < NSLOT; ++i) {
      const float wgt = acc[i] * inv;
      if (WRITE_ATTN) ab[(size_t)i * NFEAT] = wgt;
      const float ae = wgt + ATTN_EPS;
      acc[i] = ae;
      const unsigned short hh = f2bf(ae);
      const int slot = i * 32 + ((t >> 3) ^ (i & 31));
      snh[slot * 8 + (t & 7)] = (short)hh;
      snl[slot * 8 + (t & 7)] = (short)f2bf(ae - bf2f(hh));
    }
#pragma unroll
    for (int i = 0; i < NSLOT; ++i) {
      float rs = acc[i];
#pragma unroll
      for (int o = 32; o > 0; o >>= 1) rs += __shfl_down(rs, o, 64);
      if (l == 0) part[w][i] = rs;
    }
  }
  __syncthreads();
  {
    f32x4 pacc[2] = {};
#pragma unroll
    for (int ks = 0; ks < 8; ++ks) {
      bf16x8 ah[2], al[2];
#pragma unroll
      for (int m = 0; m < 2; ++m) {
        const int row = m * 16 + (l & 15);
        const int g = ks * 4 + (l >> 4);
        const int slot = row * 32 + (g ^ (row & 31));
        ah[m] = *(const bf16x8*)&snh[slot * 8];
        al[m] = *(const bf16x8*)&snl[slot * 8];
      }
      const bf16x8 bh = vreg[ks * 2 + 0];
      const bf16x8 bl2 = vreg[ks * 2 + 1];
#pragma unroll
      for (int m = 0; m < 2; ++m) {
        pacc[m] = __builtin_amdgcn_mfma_f32_16x16x32_bf16(al[m], bh, pacc[m], 0, 0, 0);
        pacc[m] = __builtin_amdgcn_mfma_f32_16x16x32_bf16(ah[m], bl2, pacc[m], 0, 0, 0);
        pacc[m] = __builtin_amdgcn_mfma_f32_16x16x32_bf16(ah[m], bh, pacc[m], 0, 0, 0);
      }
    }
    const int d = w * 16 + (l & 15);
    float* up = updp + (size_t)((b * 4 + h) * 4 + jc) * NSLOT * 64;
#pragma unroll
    for (int m = 0; m < 2; ++m)
#pragma unroll
      for (int r = 0; r < 4; ++r) {
        const int row = m * 16 + (l >> 4) * 4 + r;
        if (row < 24) up[row * 64 + d] = pacc[m][r];
      }
  }
  if (t < NSLOT)
    ssump[((size_t)(b * 4 + h) * 4 + jc) * NSLOT + t] =
        part[0][t] + part[1][t] + part[2][t] + part[3][t];
}

// ---- fused GRU (updfin fold); BK=64, 32-dim cols, grid (96,8); FINAL: + out + attnvis ----
template <bool FINAL>
__global__ LB void k_grufin(const float* __restrict__ updp, const float* __restrict__ ssump,
                            const float* __restrict__ sprev,
                            const float* __restrict__ Wih, const float* __restrict__ Whh,
                            const float* __restrict__ bih, const float* __restrict__ bhh,
                            float* __restrict__ snext, float* __restrict__ outs,
                            const float* __restrict__ attn, float* __restrict__ vis_out) {
  __shared__ float updt[8][256];
  __shared__ float Bs[3][64][33];
  const int bx = blockIdx.x;
  const int d0 = blockIdx.y * 32;
  const int rows0 = bx * 8;
  const int t = threadIdx.x;
  {
    const int h = t >> 6, d = t & 63;
#pragma unroll
    for (int u = 0; u < 8; ++u) {
      const int row = rows0 + u;
      const int b = row / 24, i = row - b * 24;
      const size_t base = (size_t)(b * 4 + h) * 4;
      float s = 0.f, wsum = 0.f;
#pragma unroll
      for (int jc = 0; jc < 4; ++jc) {
        s += updp[(base + jc) * (NSLOT * 64) + i * 64 + d];
        wsum += ssump[(base + jc) * NSLOT + i];
      }
      updt[u][h * 64 + d] = s / wsum;
    }
  }
  __syncthreads();
  const int r = t >> 5;
  const int dd = t & 31;
  float accR = 0.f, accZ = 0.f, accN = 0.f, accH = 0.f;
  for (int k0 = 0; k0 < 256; k0 += 64) {
#pragma unroll
    for (int ii = 0; ii < 6; ++ii) {
      const int i = ii * 256 + t;
      const int s = i / 512, rem = i & 511, c = rem >> 4, kq = rem & 15;
      float4 wv = *(const float4*)(Wih + (size_t)(s * 256 + d0 + c) * 256 + k0 + kq * 4);
      Bs[s][kq * 4 + 0][c] = wv.x; Bs[s][kq * 4 + 1][c] = wv.y;
      Bs[s][kq * 4 + 2][c] = wv.z; Bs[s][kq * 4 + 3][c] = wv.w;
    }
    __syncthreads();
#pragma unroll
    for (int kk = 0; kk < 64; ++kk) {
      const float a = updt[r][k0 + kk];
      accR += a * Bs[0][kk][dd];
      accZ += a * Bs[1][kk][dd];
      accN += a * Bs[2][kk][dd];
    }
    __syncthreads();
  }
  {
    const int rr2 = t >> 5, c0 = (t & 31) * 8;
    const float* sp = sprev + (size_t)(rows0 + rr2) * 256 + c0;
    *(float4*)&updt[rr2][c0] = *(const float4*)sp;
    *(float4*)&updt[rr2][c0 + 4] = *(const float4*)(sp + 4);
  }
  __syncthreads();
  for (int k0 = 0; k0 < 256; k0 += 64) {
#pragma unroll
    for (int ii = 0; ii < 6; ++ii) {
      const int i = ii * 256 + t;
      const int s = i / 512, rem = i & 511, c = rem >> 4, kq = rem & 15;
      float4 wv = *(const float4*)(Whh + (size_t)(s * 256 + d0 + c) * 256 + k0 + kq * 4);
      Bs[s][kq * 4 + 0][c] = wv.x; Bs[s][kq * 4 + 1][c] = wv.y;
      Bs[s][kq * 4 + 2][c] = wv.z; Bs[s][kq * 4 + 3][c] = wv.w;
    }
    __syncthreads();
#pragma unroll
    for (int kk = 0; kk < 64; ++kk) {
      const float a = updt[r][k0 + kk];
      accR += a * Bs[0][kk][dd];
      accZ += a * Bs[1][kk][dd];
      accH += a * Bs[2][kk][dd];
    }
    __syncthreads();
  }
  const int row = rows0 + r;
  const int c = d0 + dd;
  const float hp = updt[r][c];
  const float rr = 1.f / (1.f + expf(-(accR + bih[c] + bhh[c])));
  const float zz = 1.f / (1.f + expf(-(accZ + bih[256 + c] + bhh[256 + c])));
  const float nn = tanhf(accN + bih[512 + c] + rr * (accH + bhh[512 + c]));
  const float o = (1.f - zz) * nn + zz * hp;
  snext[(size_t)row * 256 + c] = o;
  if (FINAL) {
    outs[(size_t)row * 256 + c] = o;
    const int gid = (blockIdx.y * 96 + blockIdx.x) * 256 + t;
#pragma unroll
    for (int z = 0; z < 4; ++z) {
      const int idx = z * 196608 + gid;
      const int j = idx & 1023;
      const int rem = idx >> 10;
      const int i = rem % NSLOT;
      const int b = rem / NSLOT;
      float s = 0.f;
#pragma unroll
      for (int hh = 0; hh < NH; ++hh)
        s += attn[(size_t)((b * NH + hh) * NSLOT + i) * NFEAT + j];
      vis_out[idx] = 0.25f * s;
    }
  }
}

// ---- merged: blocks [0,768) VQ rows; [768,3840) attn_vis; last block computes commit ----
__global__ LB void k_vqvis(float* __restrict__ slots, const float* __restrict__ cb,
                           const float* __restrict__ attn,
                           float* __restrict__ idx_out, float* __restrict__ bestd2,
                           float* __restrict__ vis_out, unsigned* __restrict__ vqctr,
                           float* __restrict__ out_commit) {
  const int t = threadIdx.x;
  __shared__ float xs[256];
  __shared__ float red[256];
  __shared__ float rv[256];
  __shared__ int ri[256];
  __shared__ int amLast;
  if (blockIdx.x >= MS) {
    const int idx = (blockIdx.x - MS) * 256 + t;
    const int j = idx & 1023;
    const int rem = idx >> 10;
    const int i = rem % NSLOT;
    const int b = rem / NSLOT;
    float s = 0.f;
#pragma unroll
    for (int h = 0; h < NH; ++h)
      s += attn[(size_t)((b * NH + h) * NSLOT + i) * NFEAT + j];
    vis_out[idx] = 0.25f * s;
  } else {
    const int r = blockIdx.x;
    xs[t] = slots[(size_t)r * 256 + t];
    __syncthreads();
    red[t] = xs[t] * xs[t]; __syncthreads();
    for (int o = 128; o > 0; o >>= 1) { if (t < o) red[t] += red[t + o]; __syncthreads(); }
    const float x2 = red[0];
    float best = 1e30f; int bidx = 0;
#pragma unroll
    for (int cset = 0; cset < 2; ++cset) {
      const int c = cset * 256 + t;
      const float* cr = cb + (size_t)c * 256;
      float xc = 0.f, cc = 0.f;
      for (int dd = 0; dd < 256; dd += 4) {
        float4 cv = *(const float4*)(cr + dd);
        xc += xs[dd] * cv.x + xs[dd + 1] * cv.y + xs[dd + 2] * cv.z + xs[dd + 3] * cv.w;
        cc += cv.x * cv.x + cv.y * cv.y + cv.z * cv.z + cv.w * cv.w;
      }
      float d2 = x2 - 2.f * xc + cc;
      if (d2 < best) { best = d2; bidx = c; }
    }
    rv[t] = best; ri[t] = bidx; __syncthreads();
    for (int o = 128; o > 0; o >>= 1) {
      if (t < o) {
        if (rv[t + o] < rv[t] || (rv[t + o] == rv[t] && ri[t + o] < ri[t])) {
          rv[t] = rv[t + o]; ri[t] = ri[t + o];
        }
      }
      __syncthreads();
    }
    const int wi = ri[0];
    const float cval = cb[(size_t)wi * 256 + t];
    const float diff = xs[t] - cval;
    red[t] = diff * diff; __syncthreads();
    for (int o = 128; o > 0; o >>= 1) { if (t < o) red[t] += red[t + o]; __syncthreads(); }
    if (t == 0) { idx_out[r] = (float)wi; bestd2[r] = red[0]; }
    slots[(size_t)r * 256 + t] = cval;
  }
  // last-block commit reduction (deterministic: single block, fixed order)
  __threadfence();
  __syncthreads();
  if (t == 0) amLast = (atomicAdd(vqctr, 1u) == (unsigned)(VQVIS_BLOCKS - 1)) ? 1 : 0;
  __syncthreads();
  if (amLast) {
    __threadfence();
    float s = 0.f;
    for (int i = t; i < MS; i += 256) s += bestd2[i];
    red[t] = s; __syncthreads();
    for (int o = 128; o > 0; o >>= 1) { if (t < o) red[t] += red[t + o]; __syncthreads(); }
    if (t == 0) out_commit[0] = red[0] / (float)(MS * 256);
  }
}

extern "C" void kernel_launch(void* const* d_in, const int* in_sizes, int n_in,
                              void* d_out, int out_size, void* d_ws, size_t ws_size,
                              hipStream_t stream) {
  const float* features = (const float*)d_in[0];
  const float* cond = (const float*)d_in[1];
  const float* Wq = (const float*)d_in[2];
  const float* Wk = (const float*)d_in[3];
  const float* Wv = (const float*)d_in[4];
  const float* g_in = (const float*)d_in[5];
  const float* b_in = (const float*)d_in[6];
  const float* g_s = (const float*)d_in[7];
  const float* b_s = (const float*)d_in[8];
  const float* Wih = (const float*)d_in[9];
  const float* Whh = (const float*)d_in[10];
  const float* bih = (const float*)d_in[11];
  const float* bhh = (const float*)d_in[12];
  const float* cb = (const float*)d_in[13];
  float* out = (float*)d_out;

  char* wsb = (char*)d_ws;
  short* Bh_g = (short*)wsb; wsb += (size_t)512 * FDIM * 2;
  short* Bl_g = (short*)wsb; wsb += (size_t)512 * FDIM * 2;
  short* khi = (short*)wsb; wsb += (size_t)MF * 256 * 2;
  short* klo = (short*)wsb; wsb += (size_t)MF * 256 * 2;
  short* vThi = (short*)wsb; wsb += (size_t)MF * 256 * 2;
  short* vTlo = (short*)wsb; wsb += (size_t)MF * 256 * 2;
  short* Wgqh = (short*)wsb; wsb += (size_t)256 * 256 * 2;
  short* Wgql = (short*)wsb; wsb += (size_t)256 * 256 * 2;
  float* ws = (float*)wsb;
  float* stats = ws;  ws += 2 * MF;
  float* attn = ws;   ws += (size_t)BATCH * NH * NSLOT * NFEAT;
  float* sbufA = ws;  ws += (size_t)MS * 256;
  float* sbufB = ws;  ws += (size_t)MS * 256;
  float* updp = ws;   ws += (size_t)512 * NSLOT * 64;
  float* ssump = ws;  ws += (size_t)512 * NSLOT;
  float* cconst = ws; ws += 768;
  float* bestd2 = ws; ws += MS;
  unsigned* vqctr = (unsigned*)(ws); ws += 1;

  float* out_slots = out;
  float* out_post = out + 196608;
  float* out_pre = out + 196608 + 786432;
  float* out_idx = out + 196608 + 786432 * 2;
  float* out_commit = out_idx + 768;

  k_preprow<<<MF / 4 + 768, 256, 0, stream>>>(features, stats, Wk, Wv, Wq, g_in, b_in,
                                              g_s, b_s, Bh_g, Bl_g, Wgqh, Wgql, cconst, vqctr);
  k_mfkv<<<dim3(MF / 64, 2), 256, 0, stream>>>(features, stats, Bh_g, Bl_g, cconst,
                                               khi, klo, vThi, vTlo);

  const float* scur = cond;
  float* bufs[2] = {sbufA, sbufB};
  int nb = 0;
  for (int call = 0; call < 2; ++call) {
    for (int it = 0; it < NITER; ++it) {
      float* snxt = bufs[nb]; nb ^= 1;
      if (it == NITER - 1)
        k_fdots<true><<<512, 256, 0, stream>>>(scur, Wgqh, Wgql, cconst, khi, klo,
                                               vThi, vTlo, attn, updp, ssump);
      else
        k_fdots<false><<<512, 256, 0, stream>>>(scur, Wgqh, Wgql, cconst, khi, klo,
                                                vThi, vTlo, attn, updp, ssump);
      if (call == 1 && it == NITER - 1)
        k_grufin<true><<<dim3(MS / 8, 8), 256, 0, stream>>>(updp, ssump, scur, Wih, Whh,
                                                            bih, bhh, snxt, out_slots,
                                                            attn, out_post);
      else
        k_grufin<false><<<dim3(MS / 8, 8), 256, 0, stream>>>(updp, ssump, scur, Wih, Whh,
                                                             bih, bhh, snxt, out_slots,
                                                             nullptr, nullptr);
      scur = snxt;
    }
    if (call == 0) {
      k_vqvis<<<VQVIS_BLOCKS, 256, 0, stream>>>((float*)scur, cb, attn, out_idx, bestd2,
                                                out_pre, vqctr, out_commit);
    }
  }
}

// Round 19
// 542.108 us; speedup vs baseline: 1.4718x; 1.4718x over previous
//
#include <hip/hip_runtime.h>
#include <math.h>

#define LB __launch_bounds__(256)

constexpr int BATCH = 32, NFEAT = 1024, FDIM = 768, NSLOT = 24;
constexpr int NH = 4, DH = 64, NITER = 3;
constexpr int MF = BATCH * NFEAT;   // 32768 feature rows
constexpr int MS = BATCH * NSLOT;   // 768 slot rows
constexpr float QSCALE = 0.125f;    // dh^-0.5
constexpr float ATTN_EPS = 1e-8f;
constexpr float LNEPS = 1e-5f;

typedef __attribute__((ext_vector_type(8))) short bf16x8;
typedef __attribute__((ext_vector_type(4))) float f32x4;

__device__ __forceinline__ unsigned short f2bf(float x) {
  unsigned u = __float_as_uint(x);
  return (unsigned short)((u + 0x7FFFu + ((u >> 16) & 1u)) >> 16);
}
__device__ __forceinline__ float bf2f(unsigned short h) {
  return __uint_as_float(((unsigned)h) << 16);
}
__device__ __forceinline__ void cvt8(const float4& a, const float4& b, float m, float r,
                                     int4& hi, int4& lo) {
  float v[8] = {a.x, a.y, a.z, a.w, b.x, b.y, b.z, b.w};
  unsigned sh[8], sl[8];
#pragma unroll
  for (int j = 0; j < 8; ++j) {
    float vv = (v[j] - m) * r;
    unsigned short h = f2bf(vv);
    sh[j] = h;
    sl[j] = f2bf(vv - bf2f(h));
  }
  hi = make_int4((int)(sh[0] | (sh[1] << 16)), (int)(sh[2] | (sh[3] << 16)),
                 (int)(sh[4] | (sh[5] << 16)), (int)(sh[6] | (sh[7] << 16)));
  lo = make_int4((int)(sl[0] | (sl[1] << 16)), (int)(sl[2] | (sl[3] << 16)),
                 (int)(sl[4] | (sl[5] << 16)), (int)(sl[6] | (sl[7] << 16)));
}

// async 16B global->LDS
__device__ __forceinline__ void gll16(const void* g, void* l) {
  __builtin_amdgcn_global_load_lds(
      (const __attribute__((address_space(1))) void*)g,
      (__attribute__((address_space(3))) void*)l, 16, 0, 0);
}

// ---- merged: blocks [0,8192) rowstats; [8192,8960) weight prep ----
__global__ LB void k_preprow(const float* __restrict__ x, float* __restrict__ stats,
                             const float* __restrict__ Wk, const float* __restrict__ Wv,
                             const float* __restrict__ Wq,
                             const float* __restrict__ g_in, const float* __restrict__ b_in,
                             const float* __restrict__ g_s, const float* __restrict__ b_s,
                             short* __restrict__ Bh_g, short* __restrict__ Bl_g,
                             short* __restrict__ Wgqh, short* __restrict__ Wgql,
                             float* __restrict__ cconst) {
  const int t = threadIdx.x;
  if (blockIdx.x < MF / 4) {
    const int row = blockIdx.x * 4 + (t >> 6);
    const int lane = t & 63;
    const float* xr = x + (size_t)row * FDIM;
    float s = 0.f, sq = 0.f;
#pragma unroll
    for (int i = 0; i < 3; ++i) {
      float4 v = *(const float4*)(xr + i * 256 + lane * 4);
      s += v.x + v.y + v.z + v.w;
      sq += v.x * v.x + v.y * v.y + v.z * v.z + v.w * v.w;
    }
#pragma unroll
    for (int o = 32; o > 0; o >>= 1) { s += __shfl_down(s, o, 64); sq += __shfl_down(sq, o, 64); }
    if (lane == 0) {
      float m = s / (float)FDIM;
      float var = sq / (float)FDIM - m * m;
      stats[row * 2] = m;
      stats[row * 2 + 1] = 1.f / sqrtf(var + LNEPS);
    }
    return;
  }
  const int r = blockIdx.x - MF / 4;
  float s = 0.f;
  if (r < 512) {
    const float* srcW = (r < 256) ? (Wk + (size_t)r * FDIM) : (Wv + (size_t)(r - 256) * FDIM);
    for (int k = t; k < FDIM; k += 256) {
      float w = srcW[k];
      float wg = w * g_in[k];
      s += b_in[k] * w;
      unsigned short h = f2bf(wg);
      Bh_g[(size_t)r * FDIM + k] = (short)h;
      Bl_g[(size_t)r * FDIM + k] = (short)f2bf(wg - bf2f(h));
    }
  } else {
    const int c = r - 512;
    float w = Wq[(size_t)c * 256 + t];
    float wg = w * g_s[t];
    unsigned short hh = f2bf(wg);
    Wgqh[(size_t)c * 256 + t] = (short)hh;
    Wgql[(size_t)c * 256 + t] = (short)f2bf(wg - bf2f(hh));
    s = b_s[t] * w;
  }
  __shared__ float red[256];
  red[t] = s; __syncthreads();
  for (int o = 128; o > 0; o >>= 1) { if (t < o) red[t] += red[t + o]; __syncthreads(); }
  if (t == 0) cconst[r] = red[0];
}

// LDS union for k_mfkv: main-loop staging vs transpose-epilogue
union SmemM {
  struct { short Ah[2048], Al[2048], Bh[2][4096], Bl[2][4096]; } m;  // 40 KB
  struct { short vh[128][72], vl[128][72]; } e;                      // 36.9 KB
};

// -------- MFMA split-bf16: LN(features)@Wg^T -> k (bf16 hi/lo) AND vT (bf16 hi/lo) --------
__global__ LB void k_mfkv(const float* __restrict__ x, const float* __restrict__ stats,
                          const short* __restrict__ Bh_g, const short* __restrict__ Bl_g,
                          const float* __restrict__ cconst,
                          short* __restrict__ khi, short* __restrict__ klo,
                          short* __restrict__ vThi, short* __restrict__ vTlo) {
  __shared__ SmemM sm;
  const int t = threadIdx.x;
  const int l = t & 63;
  const int w = t >> 6;
  const int row0 = blockIdx.x * 64;
  const int c0 = blockIdx.y * 128;

  const int sAr = t >> 2;
  const int sl = t & 3;
  const int kqA = sl ^ ((sAr >> 1) & 3);
  const float* pa = x + (size_t)(row0 + sAr) * FDIM + kqA * 8;
  const float mA = stats[(row0 + sAr) * 2], rA = stats[(row0 + sAr) * 2 + 1];
  const int sBr1 = sAr + 64;
  const int kqB1 = sl ^ ((sBr1 >> 1) & 3);
  const short* pkh0 = Bh_g + (size_t)(c0 + sAr) * FDIM + kqA * 8;
  const short* pkh1 = Bh_g + (size_t)(c0 + sBr1) * FDIM + kqB1 * 8;
  const short* pkl0 = Bl_g + (size_t)(c0 + sAr) * FDIM + kqA * 8;
  const short* pkl1 = Bl_g + (size_t)(c0 + sBr1) * FDIM + kqB1 * 8;
  const short* pvh0 = Bh_g + (size_t)(256 + c0 + sAr) * FDIM + kqA * 8;
  const short* pvh1 = Bh_g + (size_t)(256 + c0 + sBr1) * FDIM + kqB1 * 8;
  const short* pvl0 = Bl_g + (size_t)(256 + c0 + sAr) * FDIM + kqA * 8;
  const short* pvl1 = Bl_g + (size_t)(256 + c0 + sBr1) * FDIM + kqB1 * 8;
  const int wbA = t * 16;
  const int wb0 = t * 16, wb1 = (t + 256) * 16;

  const int wm = (w >> 1) * 32, wn = (w & 1) * 64;
  int aoff[2], boff[4];
#pragma unroll
  for (int m = 0; m < 2; ++m) {
    const int ar = wm + m * 16 + (l & 15);
    const int kq = l >> 4;
    aoff[m] = ar * 64 + ((kq ^ ((ar >> 1) & 3)) << 4);
  }
#pragma unroll
  for (int n = 0; n < 4; ++n) {
    const int bc = wn + n * 16 + (l & 15);
    const int kq = l >> 4;
    boff[n] = bc * 64 + ((kq ^ ((bc >> 1) & 3)) << 4);
  }

  f32x4 acc[2][2][4] = {};
  float4 raa = *(const float4*)pa, rab = *(const float4*)(pa + 4);

  for (int s = 0; s < FDIM / 32; ++s) {
    if (s) __syncthreads();
    const int ko = s * 32;
    gll16(pkh0 + ko, (char*)&sm.m.Bh[0][0] + wb0);
    gll16(pkh1 + ko, (char*)&sm.m.Bh[0][0] + wb1);
    gll16(pkl0 + ko, (char*)&sm.m.Bl[0][0] + wb0);
    gll16(pkl1 + ko, (char*)&sm.m.Bl[0][0] + wb1);
    gll16(pvh0 + ko, (char*)&sm.m.Bh[1][0] + wb0);
    gll16(pvh1 + ko, (char*)&sm.m.Bh[1][0] + wb1);
    gll16(pvl0 + ko, (char*)&sm.m.Bl[1][0] + wb0);
    gll16(pvl1 + ko, (char*)&sm.m.Bl[1][0] + wb1);
    int4 hi, lo;
    cvt8(raa, rab, mA, rA, hi, lo);
    *(int4*)((char*)sm.m.Ah + wbA) = hi; *(int4*)((char*)sm.m.Al + wbA) = lo;
    if (s + 1 < FDIM / 32) {
      raa = *(const float4*)(pa + ko + 32);
      rab = *(const float4*)(pa + ko + 36);
    }
    __syncthreads();
    bf16x8 fah[2], fal[2];
#pragma unroll
    for (int m = 0; m < 2; ++m) {
      fah[m] = *(const bf16x8*)((const char*)sm.m.Ah + aoff[m]);
      fal[m] = *(const bf16x8*)((const char*)sm.m.Al + aoff[m]);
    }
#pragma unroll
    for (int kv = 0; kv < 2; ++kv) {
      bf16x8 fbh[4], fbl[4];
#pragma unroll
      for (int n = 0; n < 4; ++n) {
        fbh[n] = *(const bf16x8*)((const char*)&sm.m.Bh[kv][0] + boff[n]);
        fbl[n] = *(const bf16x8*)((const char*)&sm.m.Bl[kv][0] + boff[n]);
      }
#pragma unroll
      for (int m = 0; m < 2; ++m)
#pragma unroll
        for (int n = 0; n < 4; ++n) {
          acc[kv][m][n] = __builtin_amdgcn_mfma_f32_16x16x32_bf16(fal[m], fbh[n], acc[kv][m][n], 0, 0, 0);
          acc[kv][m][n] = __builtin_amdgcn_mfma_f32_16x16x32_bf16(fah[m], fbl[n], acc[kv][m][n], 0, 0, 0);
          acc[kv][m][n] = __builtin_amdgcn_mfma_f32_16x16x32_bf16(fah[m], fbh[n], acc[kv][m][n], 0, 0, 0);
        }
    }
  }
  __syncthreads();
  const int b_blk = row0 >> 10;
  const int jbase = row0 & 1023;
#pragma unroll
  for (int m = 0; m < 2; ++m) {
    const int rloc = wm + m * 16 + ((l >> 4) << 2);
    const int rbase = row0 + rloc;
#pragma unroll
    for (int n = 0; n < 4; ++n) {
      const int col = wn + n * 16 + (l & 15);
      const int gcol = c0 + col;
      const float cck = cconst[gcol];
      const float ccv = cconst[256 + gcol];
      unsigned vhp[2] = {0, 0}, vlp[2] = {0, 0};
#pragma unroll
      for (int r = 0; r < 4; ++r) {
        const float kval = acc[0][m][n][r] + cck;
        const unsigned short h = f2bf(kval);
        khi[(size_t)(rbase + r) * 256 + gcol] = (short)h;
        klo[(size_t)(rbase + r) * 256 + gcol] = (short)f2bf(kval - bf2f(h));
        const float vval = acc[1][m][n][r] + ccv;
        const unsigned short hv = f2bf(vval);
        const unsigned short lv = f2bf(vval - bf2f(hv));
        vhp[r >> 1] |= ((unsigned)hv) << ((r & 1) * 16);
        vlp[r >> 1] |= ((unsigned)lv) << ((r & 1) * 16);
      }
      *(int2*)((short*)&sm.e.vh[0][0] + col * 72 + rloc) = make_int2((int)vhp[0], (int)vhp[1]);
      *(int2*)((short*)&sm.e.vl[0][0] + col * 72 + rloc) = make_int2((int)vlp[0], (int)vlp[1]);
    }
  }
  __syncthreads();
  {
    const int vr = t >> 1;
    const int vh2 = (t & 1) * 32;
    const int gcol = c0 + vr;
    const int hh2 = gcol >> 6, dh = gcol & 63;
    const size_t vrow = ((size_t)(b_blk * 4 + hh2) * 64 + dh) * 1024 + jbase + vh2;
    const short* sh2 = (const short*)&sm.e.vh[0][0] + vr * 72 + vh2;
    const short* sl2 = (const short*)&sm.e.vl[0][0] + vr * 72 + vh2;
#pragma unroll
    for (int q = 0; q < 4; ++q) {
      *(int4*)(vThi + vrow + q * 8) = *(const int4*)(sh2 + q * 8);
      *(int4*)(vTlo + vrow + q * 8) = *(const int4*)(sl2 + q * 8);
    }
  }
}

// ---- fused full-MFMA fdots: register-LN + arena aliasing + K/V reg prefetch ----
template <bool WRITE_ATTN>
__global__ LB void k_fdots(const float* __restrict__ slots,
                           const short* __restrict__ Wgqh, const short* __restrict__ Wgql,
                           const float* __restrict__ cconst,
                           const short* __restrict__ khi, const short* __restrict__ klo,
                           const short* __restrict__ vThi, const short* __restrict__ vTlo,
                           float* __restrict__ attn, float* __restrict__ updp,
                           float* __restrict__ ssump) {
  const int blk = blockIdx.x;
  const int jc = blk & 3;
  const int h = (blk >> 2) & 3;
  const int b = blk >> 4;
  const int t = threadIdx.x;
  const int l = t & 63;
  const int w = t >> 6;
  __shared__ __attribute__((aligned(16))) char arena[32768];
  short* snh = (short*)arena;
  short* snl = (short*)(arena + 16384);
  float* scF = (float*)arena;
  __shared__ short qh[2048], ql[2048];
  __shared__ float part[4][NSLOT];

  const short* khb = khi + (size_t)(b * NFEAT + jc * 256) * 256 + h * 64;
  const short* klb = klo + (size_t)(b * NFEAT + jc * 256) * 256 + h * 64;
  bf16x8 kreg[16];
#pragma unroll
  for (int ks = 0; ks < 2; ++ks)
#pragma unroll
    for (int nl = 0; nl < 4; ++nl) {
      const int nt = w * 4 + nl;
      const size_t boffg = (size_t)(nt * 16 + (l & 15)) * 256 + ks * 32 + (l >> 4) * 8;
      kreg[(ks * 4 + nl) * 2 + 0] = *(const bf16x8*)(khb + boffg);
      kreg[(ks * 4 + nl) * 2 + 1] = *(const bf16x8*)(klb + boffg);
    }

  if (t < 192) {
    const int r = t >> 3, g = t & 7;
    const float* sr = slots + (size_t)(b * NSLOT + r) * 256 + g * 32;
    float4 va[8];
    float s = 0.f, sq = 0.f;
#pragma unroll
    for (int m4 = 0; m4 < 8; ++m4) {
      va[m4] = *(const float4*)(sr + m4 * 4);
      s += va[m4].x + va[m4].y + va[m4].z + va[m4].w;
      sq += va[m4].x * va[m4].x + va[m4].y * va[m4].y +
            va[m4].z * va[m4].z + va[m4].w * va[m4].w;
    }
    s += __shfl_down(s, 4, 8); sq += __shfl_down(sq, 4, 8);
    s += __shfl_down(s, 2, 8); sq += __shfl_down(sq, 2, 8);
    s += __shfl_down(s, 1, 8); sq += __shfl_down(sq, 1, 8);
    const float st = __shfl(s, l & 56, 64);
    const float sqt = __shfl(sq, l & 56, 64);
    const float mm = st * (1.f / 256.f);
    const float rr = 1.f / sqrtf(sqt * (1.f / 256.f) - mm * mm + LNEPS);
#pragma unroll
    for (int m4 = 0; m4 < 8; m4 += 2) {
      int4 hi, lo;
      cvt8(va[m4], va[m4 + 1], mm, rr, hi, lo);
      const int gi = g * 4 + (m4 >> 1);
      const int slot = r * 32 + (gi ^ (r & 31));
      *(int4*)&snh[slot * 8] = hi;
      *(int4*)&snl[slot * 8] = lo;
    }
  }
  __syncthreads();
  {
    f32x4 qacc[2] = {};
#pragma unroll
    for (int ks = 0; ks < 8; ++ks) {
      bf16x8 ah[2], al[2];
#pragma unroll
      for (int m = 0; m < 2; ++m) {
        const int row = m * 16 + (l & 15);
        const int g = ks * 4 + (l >> 4);
        const int slot = row * 32 + (g ^ (row & 31));
        ah[m] = *(const bf16x8*)&snh[slot * 8];
        al[m] = *(const bf16x8*)&snl[slot * 8];
      }
      const size_t brow = (size_t)(h * 64 + w * 16 + (l & 15)) * 256 + ks * 32 + (l >> 4) * 8;
      const bf16x8 bh = *(const bf16x8*)(Wgqh + brow);
      const bf16x8 bl2 = *(const bf16x8*)(Wgql + brow);
#pragma unroll
      for (int m = 0; m < 2; ++m) {
        qacc[m] = __builtin_amdgcn_mfma_f32_16x16x32_bf16(al[m], bh, qacc[m], 0, 0, 0);
        qacc[m] = __builtin_amdgcn_mfma_f32_16x16x32_bf16(ah[m], bl2, qacc[m], 0, 0, 0);
        qacc[m] = __builtin_amdgcn_mfma_f32_16x16x32_bf16(ah[m], bh, qacc[m], 0, 0, 0);
      }
    }
    const int d = w * 16 + (l & 15);
    const float qc = cconst[512 + h * 64 + d];
#pragma unroll
    for (int m = 0; m < 2; ++m)
#pragma unroll
      for (int r = 0; r < 4; ++r) {
        const int row = m * 16 + (l >> 4) * 4 + r;
        const float qv = qacc[m][r] + qc;
        const unsigned short hh = f2bf(qv);
        const int slot = row * 8 + ((d >> 3) ^ (row & 7));
        qh[slot * 8 + (d & 7)] = (short)hh;
        ql[slot * 8 + (d & 7)] = (short)f2bf(qv - bf2f(hh));
      }
  }
  __syncthreads();
  {
    f32x4 scc[2][4] = {};
#pragma unroll
    for (int ks = 0; ks < 2; ++ks) {
      bf16x8 ah[2], al[2];
#pragma unroll
      for (int m = 0; m < 2; ++m) {
        const int row = m * 16 + (l & 15);
        const int g = ks * 4 + (l >> 4);
        const int slot = row * 8 + (g ^ (row & 7));
        ah[m] = *(const bf16x8*)&qh[slot * 8];
        al[m] = *(const bf16x8*)&ql[slot * 8];
      }
#pragma unroll
      for (int nl = 0; nl < 4; ++nl) {
        const bf16x8 bh = kreg[(ks * 4 + nl) * 2 + 0];
        const bf16x8 bl2 = kreg[(ks * 4 + nl) * 2 + 1];
#pragma unroll
        for (int m = 0; m < 2; ++m) {
          scc[m][nl] = __builtin_amdgcn_mfma_f32_16x16x32_bf16(al[m], bh, scc[m][nl], 0, 0, 0);
          scc[m][nl] = __builtin_amdgcn_mfma_f32_16x16x32_bf16(ah[m], bl2, scc[m][nl], 0, 0, 0);
          scc[m][nl] = __builtin_amdgcn_mfma_f32_16x16x32_bf16(ah[m], bh, scc[m][nl], 0, 0, 0);
        }
      }
    }
#pragma unroll
    for (int m = 0; m < 2; ++m)
#pragma unroll
      for (int nl = 0; nl < 4; ++nl) {
        const int col = (w * 4 + nl) * 16 + (l & 15);
        const int rbase = m * 16 + ((l >> 4) << 2);
#pragma unroll
        for (int r = 0; r < 4; ++r)
          if (rbase + r < 24) scF[(rbase + r) * 256 + col] = scc[m][nl][r];
      }
  }
  bf16x8 vreg[16];
#pragma unroll
  for (int ks = 0; ks < 8; ++ks) {
    const size_t brow = ((size_t)(b * 4 + h) * 64 + w * 16 + (l & 15)) * 1024 +
                        jc * 256 + ks * 32 + (l >> 4) * 8;
    vreg[ks * 2 + 0] = *(const bf16x8*)(vThi + brow);
    vreg[ks * 2 + 1] = *(const bf16x8*)(vTlo + brow);
  }
  __syncthreads();
  float acc[NSLOT];
#pragma unroll
  for (int i = 0; i < NSLOT; ++i) acc[i] = scF[i * 256 + t];
  __syncthreads();
  {
    float mx = -1e30f;
#pragma unroll
    for (int i = 0; i < NSLOT; ++i) { acc[i] *= QSCALE; mx = fmaxf(mx, acc[i]); }
    float s = 0.f;
#pragma unroll
    for (int i = 0; i < NSLOT; ++i) { acc[i] = expf(acc[i] - mx); s += acc[i]; }
    const float inv = 1.f / s;
    float* ab = attn + (size_t)(b * NH + h) * NSLOT * NFEAT + jc * 256 + t;
#pragma unroll
    for (int i = 0; i < NSLOT; ++i) {
      const float wgt = acc[i] * inv;
      if (WRITE_ATTN) ab[(size_t)i * NFEAT] = wgt;
      const float ae = wgt + ATTN_EPS;
      acc[i] = ae;
      const unsigned short hh = f2bf(ae);
      const int slot = i * 32 + ((t >> 3) ^ (i & 31));
      snh[slot * 8 + (t & 7)] = (short)hh;
      snl[slot * 8 + (t & 7)] = (short)f2bf(ae - bf2f(hh));
    }
#pragma unroll
    for (int i = 0; i < NSLOT; ++i) {
      float rs = acc[i];
#pragma unroll
      for (int o = 32; o > 0; o >>= 1) rs += __shfl_down(rs, o, 64);
      if (l == 0) part[w][i] = rs;
    }
  }
  __syncthreads();
  {
    f32x4 pacc[2] = {};
#pragma unroll
    for (int ks = 0; ks < 8; ++ks) {
      bf16x8 ah[2], al[2];
#pragma unroll
      for (int m = 0; m < 2; ++m) {
        const int row = m * 16 + (l & 15);
        const int g = ks * 4 + (l >> 4);
        const int slot = row * 32 + (g ^ (row & 31));
        ah[m] = *(const bf16x8*)&snh[slot * 8];
        al[m] = *(const bf16x8*)&snl[slot * 8];
      }
      const bf16x8 bh = vreg[ks * 2 + 0];
      const bf16x8 bl2 = vreg[ks * 2 + 1];
#pragma unroll
      for (int m = 0; m < 2; ++m) {
        pacc[m] = __builtin_amdgcn_mfma_f32_16x16x32_bf16(al[m], bh, pacc[m], 0, 0, 0);
        pacc[m] = __builtin_amdgcn_mfma_f32_16x16x32_bf16(ah[m], bl2, pacc[m], 0, 0, 0);
        pacc[m] = __builtin_amdgcn_mfma_f32_16x16x32_bf16(ah[m], bh, pacc[m], 0, 0, 0);
      }
    }
    const int d = w * 16 + (l & 15);
    float* up = updp + (size_t)((b * 4 + h) * 4 + jc) * NSLOT * 64;
#pragma unroll
    for (int m = 0; m < 2; ++m)
#pragma unroll
      for (int r = 0; r < 4; ++r) {
        const int row = m * 16 + (l >> 4) * 4 + r;
        if (row < 24) up[row * 64 + d] = pacc[m][r];
      }
  }
  if (t < NSLOT)
    ssump[((size_t)(b * 4 + h) * 4 + jc) * NSLOT + t] =
        part[0][t] + part[1][t] + part[2][t] + part[3][t];
}

// ---- fused GRU (updfin fold); BK=64; FINAL: + out + attnvis; commit fold (fence-free) ----
template <bool FINAL>
__global__ LB void k_grufin(const float* __restrict__ updp, const float* __restrict__ ssump,
                            const float* __restrict__ sprev,
                            const float* __restrict__ Wih, const float* __restrict__ Whh,
                            const float* __restrict__ bih, const float* __restrict__ bhh,
                            float* __restrict__ snext, float* __restrict__ outs,
                            const float* __restrict__ attn, float* __restrict__ vis_out,
                            const float* __restrict__ bestd2c, float* __restrict__ commit_out) {
  __shared__ float updt[8][256];
  __shared__ float Bs[3][64][33];
  const int bx = blockIdx.x;
  const int d0 = blockIdx.y * 32;
  const int rows0 = bx * 8;
  const int t = threadIdx.x;
  // fence-free commit fold: bestd2 was fully written by the preceding k_vqvis launch
  // (kernel-boundary ordering); block (0,0) of this launch reduces it. Deterministic.
  if (commit_out != nullptr && bx == 0 && blockIdx.y == 0) {
    float s = 0.f;
    for (int i = t; i < MS; i += 256) s += bestd2c[i];
    float* red = &Bs[0][0][0];
    red[t] = s; __syncthreads();
    for (int o = 128; o > 0; o >>= 1) { if (t < o) red[t] += red[t + o]; __syncthreads(); }
    if (t == 0) commit_out[0] = red[0] / (float)(MS * 256);
    __syncthreads();
  }
  {
    const int h = t >> 6, d = t & 63;
#pragma unroll
    for (int u = 0; u < 8; ++u) {
      const int row = rows0 + u;
      const int b = row / 24, i = row - b * 24;
      const size_t base = (size_t)(b * 4 + h) * 4;
      float s = 0.f, wsum = 0.f;
#pragma unroll
      for (int jc = 0; jc < 4; ++jc) {
        s += updp[(base + jc) * (NSLOT * 64) + i * 64 + d];
        wsum += ssump[(base + jc) * NSLOT + i];
      }
      updt[u][h * 64 + d] = s / wsum;
    }
  }
  __syncthreads();
  const int r = t >> 5;
  const int dd = t & 31;
  float accR = 0.f, accZ = 0.f, accN = 0.f, accH = 0.f;
  for (int k0 = 0; k0 < 256; k0 += 64) {
#pragma unroll
    for (int ii = 0; ii < 6; ++ii) {
      const int i = ii * 256 + t;
      const int s = i / 512, rem = i & 511, c = rem >> 4, kq = rem & 15;
      float4 wv = *(const float4*)(Wih + (size_t)(s * 256 + d0 + c) * 256 + k0 + kq * 4);
      Bs[s][kq * 4 + 0][c] = wv.x; Bs[s][kq * 4 + 1][c] = wv.y;
      Bs[s][kq * 4 + 2][c] = wv.z; Bs[s][kq * 4 + 3][c] = wv.w;
    }
    __syncthreads();
#pragma unroll
    for (int kk = 0; kk < 64; ++kk) {
      const float a = updt[r][k0 + kk];
      accR += a * Bs[0][kk][dd];
      accZ += a * Bs[1][kk][dd];
      accN += a * Bs[2][kk][dd];
    }
    __syncthreads();
  }
  {
    const int rr2 = t >> 5, c0 = (t & 31) * 8;
    const float* sp = sprev + (size_t)(rows0 + rr2) * 256 + c0;
    *(float4*)&updt[rr2][c0] = *(const float4*)sp;
    *(float4*)&updt[rr2][c0 + 4] = *(const float4*)(sp + 4);
  }
  __syncthreads();
  for (int k0 = 0; k0 < 256; k0 += 64) {
#pragma unroll
    for (int ii = 0; ii < 6; ++ii) {
      const int i = ii * 256 + t;
      const int s = i / 512, rem = i & 511, c = rem >> 4, kq = rem & 15;
      float4 wv = *(const float4*)(Whh + (size_t)(s * 256 + d0 + c) * 256 + k0 + kq * 4);
      Bs[s][kq * 4 + 0][c] = wv.x; Bs[s][kq * 4 + 1][c] = wv.y;
      Bs[s][kq * 4 + 2][c] = wv.z; Bs[s][kq * 4 + 3][c] = wv.w;
    }
    __syncthreads();
#pragma unroll
    for (int kk = 0; kk < 64; ++kk) {
      const float a = updt[r][k0 + kk];
      accR += a * Bs[0][kk][dd];
      accZ += a * Bs[1][kk][dd];
      accH += a * Bs[2][kk][dd];
    }
    __syncthreads();
  }
  const int row = rows0 + r;
  const int c = d0 + dd;
  const float hp = updt[r][c];
  const float rr = 1.f / (1.f + expf(-(accR + bih[c] + bhh[c])));
  const float zz = 1.f / (1.f + expf(-(accZ + bih[256 + c] + bhh[256 + c])));
  const float nn = tanhf(accN + bih[512 + c] + rr * (accH + bhh[512 + c]));
  const float o = (1.f - zz) * nn + zz * hp;
  snext[(size_t)row * 256 + c] = o;
  if (FINAL) {
    outs[(size_t)row * 256 + c] = o;
    const int gid = (blockIdx.y * 96 + blockIdx.x) * 256 + t;
#pragma unroll
    for (int z = 0; z < 4; ++z) {
      const int idx = z * 196608 + gid;
      const int j = idx & 1023;
      const int rem = idx >> 10;
      const int i = rem % NSLOT;
      const int b = rem / NSLOT;
      float s = 0.f;
#pragma unroll
      for (int hh = 0; hh < NH; ++hh)
        s += attn[(size_t)((b * NH + hh) * NSLOT + i) * NFEAT + j];
      vis_out[idx] = 0.25f * s;
    }
  }
}

// ---- merged: blocks [0,768) VQ rows; [768, 768+3072) attn_vis (call 0) ----
__global__ LB void k_vqvis(float* __restrict__ slots, const float* __restrict__ cb,
                           const float* __restrict__ attn,
                           float* __restrict__ idx_out, float* __restrict__ bestd2,
                           float* __restrict__ vis_out) {
  const int t = threadIdx.x;
  if (blockIdx.x >= MS) {
    const int idx = (blockIdx.x - MS) * 256 + t;
    const int j = idx & 1023;
    const int rem = idx >> 10;
    const int i = rem % NSLOT;
    const int b = rem / NSLOT;
    float s = 0.f;
#pragma unroll
    for (int h = 0; h < NH; ++h)
      s += attn[(size_t)((b * NH + h) * NSLOT + i) * NFEAT + j];
    vis_out[idx] = 0.25f * s;
    return;
  }
  const int r = blockIdx.x;
  __shared__ float xs[256];
  __shared__ float red[256];
  __shared__ float rv[256];
  __shared__ int ri[256];
  xs[t] = slots[(size_t)r * 256 + t];
  __syncthreads();
  red[t] = xs[t] * xs[t]; __syncthreads();
  for (int o = 128; o > 0; o >>= 1) { if (t < o) red[t] += red[t + o]; __syncthreads(); }
  const float x2 = red[0];
  float best = 1e30f; int bidx = 0;
#pragma unroll
  for (int cset = 0; cset < 2; ++cset) {
    const int c = cset * 256 + t;
    const float* cr = cb + (size_t)c * 256;
    float xc = 0.f, cc = 0.f;
    for (int dd = 0; dd < 256; dd += 4) {
      float4 cv = *(const float4*)(cr + dd);
      xc += xs[dd] * cv.x + xs[dd + 1] * cv.y + xs[dd + 2] * cv.z + xs[dd + 3] * cv.w;
      cc += cv.x * cv.x + cv.y * cv.y + cv.z * cv.z + cv.w * cv.w;
    }
    float d2 = x2 - 2.f * xc + cc;
    if (d2 < best) { best = d2; bidx = c; }
  }
  rv[t] = best; ri[t] = bidx; __syncthreads();
  for (int o = 128; o > 0; o >>= 1) {
    if (t < o) {
      if (rv[t + o] < rv[t] || (rv[t + o] == rv[t] && ri[t + o] < ri[t])) {
        rv[t] = rv[t + o]; ri[t] = ri[t + o];
      }
    }
    __syncthreads();
  }
  const int wi = ri[0];
  const float cval = cb[(size_t)wi * 256 + t];
  const float diff = xs[t] - cval;
  red[t] = diff * diff; __syncthreads();
  for (int o = 128; o > 0; o >>= 1) { if (t < o) red[t] += red[t + o]; __syncthreads(); }
  if (t == 0) { idx_out[r] = (float)wi; bestd2[r] = red[0]; }
  slots[(size_t)r * 256 + t] = cval;
}

extern "C" void kernel_launch(void* const* d_in, const int* in_sizes, int n_in,
                              void* d_out, int out_size, void* d_ws, size_t ws_size,
                              hipStream_t stream) {
  const float* features = (const float*)d_in[0];
  const float* cond = (const float*)d_in[1];
  const float* Wq = (const float*)d_in[2];
  const float* Wk = (const float*)d_in[3];
  const float* Wv = (const float*)d_in[4];
  const float* g_in = (const float*)d_in[5];
  const float* b_in = (const float*)d_in[6];
  const float* g_s = (const float*)d_in[7];
  const float* b_s = (const float*)d_in[8];
  const float* Wih = (const float*)d_in[9];
  const float* Whh = (const float*)d_in[10];
  const float* bih = (const float*)d_in[11];
  const float* bhh = (const float*)d_in[12];
  const float* cb = (const float*)d_in[13];
  float* out = (float*)d_out;

  char* wsb = (char*)d_ws;
  short* Bh_g = (short*)wsb; wsb += (size_t)512 * FDIM * 2;
  short* Bl_g = (short*)wsb; wsb += (size_t)512 * FDIM * 2;
  short* khi = (short*)wsb; wsb += (size_t)MF * 256 * 2;
  short* klo = (short*)wsb; wsb += (size_t)MF * 256 * 2;
  short* vThi = (short*)wsb; wsb += (size_t)MF * 256 * 2;
  short* vTlo = (short*)wsb; wsb += (size_t)MF * 256 * 2;
  short* Wgqh = (short*)wsb; wsb += (size_t)256 * 256 * 2;
  short* Wgql = (short*)wsb; wsb += (size_t)256 * 256 * 2;
  float* ws = (float*)wsb;
  float* stats = ws;  ws += 2 * MF;
  float* attn = ws;   ws += (size_t)BATCH * NH * NSLOT * NFEAT;
  float* sbufA = ws;  ws += (size_t)MS * 256;
  float* sbufB = ws;  ws += (size_t)MS * 256;
  float* updp = ws;   ws += (size_t)512 * NSLOT * 64;
  float* ssump = ws;  ws += (size_t)512 * NSLOT;
  float* cconst = ws; ws += 768;
  float* bestd2 = ws; ws += MS;

  float* out_slots = out;
  float* out_post = out + 196608;
  float* out_pre = out + 196608 + 786432;
  float* out_idx = out + 196608 + 786432 * 2;
  float* out_commit = out_idx + 768;

  k_preprow<<<MF / 4 + 768, 256, 0, stream>>>(features, stats, Wk, Wv, Wq, g_in, b_in,
                                              g_s, b_s, Bh_g, Bl_g, Wgqh, Wgql, cconst);
  k_mfkv<<<dim3(MF / 64, 2), 256, 0, stream>>>(features, stats, Bh_g, Bl_g, cconst,
                                               khi, klo, vThi, vTlo);

  const float* scur = cond;
  float* bufs[2] = {sbufA, sbufB};
  int nb = 0;
  for (int call = 0; call < 2; ++call) {
    for (int it = 0; it < NITER; ++it) {
      float* snxt = bufs[nb]; nb ^= 1;
      if (it == NITER - 1)
        k_fdots<true><<<512, 256, 0, stream>>>(scur, Wgqh, Wgql, cconst, khi, klo,
                                               vThi, vTlo, attn, updp, ssump);
      else
        k_fdots<false><<<512, 256, 0, stream>>>(scur, Wgqh, Wgql, cconst, khi, klo,
                                                vThi, vTlo, attn, updp, ssump);
      const bool doCommit = (call == 1 && it == 0);
      if (call == 1 && it == NITER - 1)
        k_grufin<true><<<dim3(MS / 8, 8), 256, 0, stream>>>(updp, ssump, scur, Wih, Whh,
                                                            bih, bhh, snxt, out_slots,
                                                            attn, out_post,
                                                            nullptr, nullptr);
      else
        k_grufin<false><<<dim3(MS / 8, 8), 256, 0, stream>>>(updp, ssump, scur, Wih, Whh,
                                                             bih, bhh, snxt, out_slots,
                                                             nullptr, nullptr,
                                                             doCommit ? bestd2 : nullptr,
                                                             doCommit ? out_commit : nullptr);
      scur = snxt;
    }
    if (call == 0) {
      k_vqvis<<<MS + BATCH * NSLOT * NFEAT / 256, 256, 0, stream>>>(
          (float*)scur, cb, attn, out_idx, bestd2, out_pre);
    }
  }
}